// Round 6
// baseline (6109.130 us; speedup 1.0000x reference)
//
#include <hip/hip_runtime.h>

typedef short bf16x8 __attribute__((ext_vector_type(8)));
typedef float f32x4 __attribute__((ext_vector_type(4)));
typedef unsigned short us8 __attribute__((ext_vector_type(8)));

#define B_ 256
#define T_ 1024
#define H_ 512
#define E_ 256
#define O_ 256
#define V_ 256

__device__ __align__(16) unsigned int   g_P2[V_ * 256];   // P=emb@Wx^T+b, packed u32 pairs (256 KB)
__device__ __align__(16) unsigned short g_Whf[H_ * H_];   // Wh in MFMA B-frag layout (512 KB)
__device__ __align__(16) unsigned short g_Wdf[O_ * H_];   // Wd in MFMA B-frag layout (256 KB)

__device__ __forceinline__ unsigned short f2bf(float f) {
    union { float f; unsigned int u; } v; v.f = f;
    unsigned int r = v.u + 0x7fffu + ((v.u >> 16) & 1u);   // RNE
    return (unsigned short)(r >> 16);
}
__device__ __forceinline__ float bf2f(unsigned short s) {
    union { unsigned int u; float f; } v; v.u = ((unsigned int)s) << 16;
    return v.f;
}

// ---------------- K1a: P2[v] = packed(b + emb[v] @ Wx^T) ----------------
__global__ void k_embWx(const float* __restrict__ emb, const float* __restrict__ W,
                        const float* __restrict__ bb) {
    __shared__ float e[E_];
    int v = blockIdx.x;
    e[threadIdx.x] = emb[(size_t)v * E_ + threadIdx.x];
    __syncthreads();
#pragma unroll
    for (int rep = 0; rep < 2; rep++) {
        int n = threadIdx.x + rep * 256;
        const float4* wr4 = (const float4*)(W + (size_t)n * (E_ + H_));
        float s = bb[n];
        for (int k = 0; k < E_ / 4; k++) {
            float4 wv = wr4[k];
            s += e[4*k] * wv.x + e[4*k+1] * wv.y + e[4*k+2] * wv.z + e[4*k+3] * wv.w;
        }
        int w = n >> 6, r6 = n & 63;
        int lo = r6 & 15, nt = r6 >> 4;
        int p = nt >> 1, half = nt & 1;
        ((unsigned short*)g_P2)[(v * 256 + w * 32 + lo * 2 + p) * 2 + half] = f2bf(s);
    }
}

// ---------------- K1b/K1c: weight -> MFMA B-fragment layout (bf16) ----------------
// Tile (nt,kt): lane l, elem j holds  Wmat[n = nt*16 + (l&15)][k = kt*32 + (l>>4)*8 + j]
__global__ void k_fragWh(const float* __restrict__ W) {
    int gid = blockIdx.x * blockDim.x + threadIdx.x;   // 512 tiles * 64 lanes
    int l = gid & 63, tile = gid >> 6;
    int kt = tile & 15, nt = tile >> 4;
    int n = nt * 16 + (l & 15), k0 = kt * 32 + (l >> 4) * 8;
    const float* src = W + (size_t)n * (E_ + H_) + E_ + k0;   // Wh = W[:,256:]
#pragma unroll
    for (int j = 0; j < 8; j++) g_Whf[(size_t)gid * 8 + j] = f2bf(src[j]);
}
__global__ void k_fragWd(const float* __restrict__ Wd) {
    int gid = blockIdx.x * blockDim.x + threadIdx.x;   // 256 tiles * 64 lanes
    int l = gid & 63, tile = gid >> 6;
    int kt = tile & 15, nt = tile >> 4;
    int n = nt * 16 + (l & 15), k0 = kt * 32 + (l >> 4) * 8;
    const float* src = Wd + (size_t)n * H_ + k0;
#pragma unroll
    for (int j = 0; j < 8; j++) g_Wdf[(size_t)gid * 8 + j] = f2bf(src[j]);
}

// ---------------- K2: recurrence — 3 kt in regs, 13 kt STREAMED from L2 ----------------
// 16 blocks x 16 batch rows; 512 thr = 8 waves; wave w owns n-tiles 4w..4w+3.
// Allocator empirics (R1-R5): grant = 65536/threads regs, attributes ignored; demand
// over grant -> L2-scratch whole-array spill with latency-serialized reloads (~10k
// cy/step). So: demand ~115 < 128 by design. Wh kt 0..2 pinned (48 VGPRs); kt 3..15
// streamed per step via global_load_lds (16B, no VGPR round-trip) into a 4-deep ring
// of 32KB LDS chunks. Per-wave-private chunk regions -> no barrier per chunk; counted
// vmcnt(12/8/4/0) only (hs stores never drained in-loop); sched_barrier(0) pins keep
// the vm FIFO counts sound; lgkmcnt(0) before re-issue guards buffer reuse.
// LDS: 128 KB ring + 2x16 KB h dbuf (XOR-swizzle byte^=(row&7)<<4) = 160 KB.
#define ISSUE_CK(KT_, CB_) do {                                                        \
    __builtin_amdgcn_sched_barrier(0);                                                 \
    _Pragma("unroll")                                                                  \
    for (int nt_ = 0; nt_ < 4; nt_++) {                                                \
        const unsigned short* gp_ = g_Whf + ((w4 + nt_) * 16 + (KT_)) * 512 + l * 8;   \
        __builtin_amdgcn_global_load_lds(                                              \
            (const __attribute__((address_space(1))) unsigned int*)gp_,                \
            (__attribute__((address_space(3))) unsigned int*)                          \
                (lds_ck + (CB_) * 16384 + w * 2048 + nt_ * 512),                       \
            16, 0, 0);                                                                 \
    }                                                                                  \
    __builtin_amdgcn_sched_barrier(0);                                                 \
} while (0)

#define CONS_CK(I_, VMS_) do {                                                         \
    asm volatile("s_waitcnt vmcnt(" VMS_ ")" ::: "memory");                            \
    __builtin_amdgcn_sched_barrier(0);                                                 \
    bf16x8 a_ = *(const bf16x8*)(hb + lo * 1024 + (((3 + (I_)) * 64 + hi * 16) ^ sw)); \
    const char* cp_ = (const char*)lds_ck + ((I_) & 3) * 32768 + w * 4096 + l * 16;    \
    bf16x8 b0_ = *(const bf16x8*)(cp_);                                                \
    bf16x8 b1_ = *(const bf16x8*)(cp_ + 1024);                                         \
    bf16x8 b2_ = *(const bf16x8*)(cp_ + 2048);                                         \
    bf16x8 b3_ = *(const bf16x8*)(cp_ + 3072);                                         \
    acc[0] = __builtin_amdgcn_mfma_f32_16x16x32_bf16(a_, b0_, acc[0], 0, 0, 0);        \
    acc[1] = __builtin_amdgcn_mfma_f32_16x16x32_bf16(a_, b1_, acc[1], 0, 0, 0);        \
    acc[2] = __builtin_amdgcn_mfma_f32_16x16x32_bf16(a_, b2_, acc[2], 0, 0, 0);        \
    acc[3] = __builtin_amdgcn_mfma_f32_16x16x32_bf16(a_, b3_, acc[3], 0, 0, 0);        \
    asm volatile("s_waitcnt lgkmcnt(0)" ::: "memory");                                 \
    __builtin_amdgcn_sched_barrier(0);                                                 \
} while (0)

__global__ void __launch_bounds__(512) k_rnn(const int* __restrict__ x,
                                             const float* __restrict__ h0,
                                             float* __restrict__ out) {
    __shared__ __align__(16) unsigned short lds_ck[4 * 16384];    // 128 KB: 4x32KB ring
    __shared__ __align__(16) unsigned short lds_h[2][16 * 512];   // 2 x 16 KB
    const int tid = threadIdx.x;
    const int w = tid >> 6, l = tid & 63;
    const int hi = l >> 4, lo = l & 15;
    const int r0 = blockIdx.x * 16;
    const int w4 = w * 4;
    const int nb = w * 64 + lo;                 // n = nb + nt*16, nt 0..3
    const int sw = (lo & 7) << 4;               // A-read swizzle

    // pinned B-fragments kt 0..2 (4 nt x 3 kt = 12 frags = 48 VGPRs)
    bf16x8 breg[4][3];
#pragma unroll
    for (int nt = 0; nt < 4; nt++)
#pragma unroll
        for (int kt = 0; kt < 3; kt++)
            breg[nt][kt] = *(const bf16x8*)(g_Whf + ((w4 + nt) * 16 + kt) * 512 + l * 8);

    // stage h0 (fp32 -> bf16, swizzled) into buffer 0
    {
        int row = tid >> 5;
        int c = (tid & 31) * 16;
        const float* hsrc = h0 + (size_t)(r0 + row) * H_ + c;
        us8 va, vb;
#pragma unroll
        for (int i = 0; i < 8; i++) ((unsigned short*)&va)[i] = f2bf(hsrc[i]);
#pragma unroll
        for (int i = 0; i < 8; i++) ((unsigned short*)&vb)[i] = f2bf(hsrc[8 + i]);
        char* hbw = (char*)lds_h[0] + row * 1024;
        int cb = c * 2;
        *(us8*)(hbw + ((cb)      ^ ((row & 7) << 4))) = va;
        *(us8*)(hbw + ((cb + 16) ^ ((row & 7) << 4))) = vb;
    }

    // x for t=0 (thread's 4 batch rows: r = hi*4+rg)
    int xs0 = x[(r0 + hi * 4 + 0) * T_];
    int xs1 = x[(r0 + hi * 4 + 1) * T_];
    int xs2 = x[(r0 + hi * 4 + 2) * T_];
    int xs3 = x[(r0 + hi * 4 + 3) * T_];

    // per-thread hs element offsets (max ~134M < 2^31)
    const int eo0 = (r0 + hi * 4 + 0) * (T_ * H_) + nb;
    const int eo1 = (r0 + hi * 4 + 1) * (T_ * H_) + nb;
    const int eo2 = (r0 + hi * 4 + 2) * (T_ * H_) + nb;
    const int eo3 = (r0 + hi * 4 + 3) * (T_ * H_) + nb;

    __syncthreads();

    unsigned short* hs = (unsigned short*)out;   // hs[b,t] bf16 in-place in d_out

#pragma unroll 1
    for (int t = 0; t < T_; t++) {
        const int c = t & 1;
        const char* hb = (const char*)lds_h[c];

        // u = P[x[r,t]] packed loads (4 x 8 B), consumed in epilogue
        unsigned up[4][2];
        {
            const int pb = (w << 5) + (lo << 1);
            *(uint2*)&up[0][0] = *(const uint2*)(g_P2 + (xs0 << 8) + pb);
            *(uint2*)&up[1][0] = *(const uint2*)(g_P2 + (xs1 << 8) + pb);
            *(uint2*)&up[2][0] = *(const uint2*)(g_P2 + (xs2 << 8) + pb);
            *(uint2*)&up[3][0] = *(const uint2*)(g_P2 + (xs3 << 8) + pb);
        }
        // prefetch x for t+1
        {
            const int tn = (t < T_ - 1) ? t + 1 : t;
            xs0 = x[(r0 + hi * 4 + 0) * T_ + tn];
            xs1 = x[(r0 + hi * 4 + 1) * T_ + tn];
            xs2 = x[(r0 + hi * 4 + 2) * T_ + tn];
            xs3 = x[(r0 + hi * 4 + 3) * T_ + tn];
        }

        // prime the stream: chunks 0..3 (kt 3..6) into ring bufs 0..3
        ISSUE_CK(3, 0);
        ISSUE_CK(4, 1);
        ISSUE_CK(5, 2);
        ISSUE_CK(6, 3);

        // reg phase: kt 0..2 while the stream flies
        f32x4 acc[4];
#pragma unroll
        for (int nt = 0; nt < 4; nt++) { acc[nt][0] = 0.f; acc[nt][1] = 0.f; acc[nt][2] = 0.f; acc[nt][3] = 0.f; }
#pragma unroll
        for (int kt = 0; kt < 3; kt++) {
            bf16x8 a = *(const bf16x8*)(hb + lo * 1024 + ((kt * 64 + hi * 16) ^ sw));
            acc[0] = __builtin_amdgcn_mfma_f32_16x16x32_bf16(a, breg[0][kt], acc[0], 0, 0, 0);
            acc[1] = __builtin_amdgcn_mfma_f32_16x16x32_bf16(a, breg[1][kt], acc[1], 0, 0, 0);
            acc[2] = __builtin_amdgcn_mfma_f32_16x16x32_bf16(a, breg[2][kt], acc[2], 0, 0, 0);
            acc[3] = __builtin_amdgcn_mfma_f32_16x16x32_bf16(a, breg[3][kt], acc[3], 0, 0, 0);
        }

        // streamed phase: consume chunk i (kt=3+i), re-issue chunk i+4 (kt=7+i)
        CONS_CK(0, "12"); ISSUE_CK(7, 0);
        CONS_CK(1, "12"); ISSUE_CK(8, 1);
        CONS_CK(2, "12"); ISSUE_CK(9, 2);
        CONS_CK(3, "12"); ISSUE_CK(10, 3);
        CONS_CK(4, "12"); ISSUE_CK(11, 0);
        CONS_CK(5, "12"); ISSUE_CK(12, 1);
        CONS_CK(6, "12"); ISSUE_CK(13, 2);
        CONS_CK(7, "12"); ISSUE_CK(14, 3);
        CONS_CK(8, "12"); ISSUE_CK(15, 0);
        CONS_CK(9, "12");
        CONS_CK(10, "8");
        CONS_CK(11, "4");
        CONS_CK(12, "0");

        // epilogue: h_next = tanh(acc + u); hs stores (never drained) + lds_h[c^1]
        char* hw = (char*)lds_h[c ^ 1];
        const int tb = t << 9;               // t*H_
#pragma unroll
        for (int nt = 0; nt < 4; nt++) {
            const int n = nb + nt * 16;
#pragma unroll
            for (int rg = 0; rg < 4; rg++) {
                const int r = hi * 4 + rg;   // C/D row = (lane>>4)*4 + reg  [m89]
                const unsigned uw = up[rg][nt >> 1];
                const float uf = bf2f((nt & 1) ? (unsigned short)(uw >> 16)
                                               : (unsigned short)(uw & 0xffffu));
                float v = acc[nt][rg] + uf;
                float ex = __expf(v + v);
                float th = 1.f - __fdividef(2.f, ex + 1.f);   // tanh
                unsigned short hv = f2bf(th);
                const int eo = (rg == 0) ? eo0 : (rg == 1) ? eo1 : (rg == 2) ? eo2 : eo3;
                hs[eo + tb + nt * 16] = hv;
                *(unsigned short*)(hw + r * 1024 + ((2 * n) ^ ((r & 7) << 4))) = hv;
            }
        }

        // single barrier: LDS visibility only
        __builtin_amdgcn_sched_barrier(0);
        asm volatile("s_waitcnt lgkmcnt(0)" ::: "memory");
        __builtin_amdgcn_s_barrier();
        __builtin_amdgcn_sched_barrier(0);
    }

    // h_final (fp32) from lds_h[0]
    float* hfin = out + (size_t)B_ * T_ * O_;
#pragma unroll
    for (int nt = 0; nt < 4; nt++)
#pragma unroll
        for (int rg = 0; rg < 4; rg++) {
            const int r = hi * 4 + rg;
            const int n = nb + nt * 16;
            unsigned short hv = *(const unsigned short*)((const char*)lds_h[0] + r * 1024 +
                                                         ((2 * n) ^ ((r & 7) << 4)));
            hfin[(r0 + r) * H_ + n] = bf2f(hv);
        }
}

// ---------------- K3: outputs = hs @ Wd^T + bd, in-place over hs slots ----------------
__launch_bounds__(512, 2)
__global__ void k_out(const float* __restrict__ bd, float* out) {
    int tid = threadIdx.x;
    int w = tid >> 6, l = tid & 63;
    int hi = l >> 4, lo = l & 15;
    size_t m0 = (size_t)blockIdx.x * 256 + w * 32;
    const unsigned short* hsb = (const unsigned short*)out;
    float bdv[16];
#pragma unroll
    for (int nt = 0; nt < 16; nt++) bdv[nt] = bd[nt * 16 + lo];
    f32x4 acc[2][16];
#pragma unroll
    for (int m = 0; m < 2; m++)
#pragma unroll
        for (int nt = 0; nt < 16; nt++) { acc[m][nt][0] = 0.f; acc[m][nt][1] = 0.f; acc[m][nt][2] = 0.f; acc[m][nt][3] = 0.f; }
#pragma unroll 2
    for (int kt = 0; kt < 16; kt++) {
        bf16x8 a0 = *(const bf16x8*)(hsb + (m0 + lo) * 512 + kt * 32 + hi * 8);
        bf16x8 a1 = *(const bf16x8*)(hsb + (m0 + 16 + lo) * 512 + kt * 32 + hi * 8);
#pragma unroll
        for (int nt = 0; nt < 16; nt++) {
            bf16x8 bf = *(const bf16x8*)(g_Wdf + (size_t)(nt * 16 + kt) * 512 + l * 8);
            acc[0][nt] = __builtin_amdgcn_mfma_f32_16x16x32_bf16(a0, bf, acc[0][nt], 0, 0, 0);
            acc[1][nt] = __builtin_amdgcn_mfma_f32_16x16x32_bf16(a1, bf, acc[1][nt], 0, 0, 0);
        }
    }
#pragma unroll
    for (int m = 0; m < 2; m++)
#pragma unroll
        for (int nt = 0; nt < 16; nt++)
#pragma unroll
            for (int rg = 0; rg < 4; rg++) {
                size_t row = m0 + m * 16 + hi * 4 + rg;
                out[row * O_ + nt * 16 + lo] = acc[m][nt][rg] + bdv[nt];
            }
}

extern "C" void kernel_launch(void* const* d_in, const int* in_sizes, int n_in,
                              void* d_out, int out_size, void* d_ws, size_t ws_size,
                              hipStream_t stream) {
    const int*   x   = (const int*)d_in[0];
    const float* h0  = (const float*)d_in[1];
    const float* emb = (const float*)d_in[2];
    const float* W   = (const float*)d_in[3];
    const float* b   = (const float*)d_in[4];
    const float* Wd  = (const float*)d_in[5];
    const float* bd  = (const float*)d_in[6];
    float* out = (float*)d_out;

    k_embWx<<<dim3(V_), dim3(256), 0, stream>>>(emb, W, b);
    k_fragWh<<<dim3(128), dim3(256), 0, stream>>>(W);
    k_fragWd<<<dim3(64), dim3(256), 0, stream>>>(Wd);
    k_rnn<<<dim3(16), dim3(512), 0, stream>>>(x, h0, out);
    k_out<<<dim3(1024), dim3(512), 0, stream>>>(bd, out);
}

// Round 7
// 3717.170 us; speedup vs baseline: 1.6435x; 1.6435x over previous
//
#include <hip/hip_runtime.h>

typedef short bf16x8 __attribute__((ext_vector_type(8)));
typedef float f32x4 __attribute__((ext_vector_type(4)));
typedef unsigned short us8 __attribute__((ext_vector_type(8)));

#define B_ 256
#define T_ 1024
#define H_ 512
#define E_ 256
#define O_ 256
#define V_ 256

// Prepped operands in device globals: no ws_size assumptions, graph-safe,
// rewritten deterministically every launch.
__device__ __align__(16) unsigned short g_P[V_ * H_];     // P = emb@Wx^T + b, bf16 (256 KB)
__device__ __align__(16) unsigned short g_Whf[H_ * H_];   // Wh in MFMA B-frag layout (512 KB)
__device__ __align__(16) unsigned short g_Wdf[O_ * H_];   // Wd in MFMA B-frag layout (256 KB)

// Cross-block h exchange: parity-double-buffered, agent-scope (L3-coherent).
// Layout: [parity][ (g*512 + n)*8 + r/2 ] u32 = (h[r_even] | h[r_odd]<<16).
__device__ __align__(16) unsigned g_ex[2][16 * 512 * 8];  // 2 x 256 KB
__device__ unsigned g_flag[16 * 64];                      // 1 counter/group, 256B padded

__device__ __forceinline__ unsigned short f2bf(float f) {
    union { float f; unsigned int u; } v; v.f = f;
    unsigned int r = v.u + 0x7fffu + ((v.u >> 16) & 1u);   // RNE
    return (unsigned short)(r >> 16);
}
__device__ __forceinline__ float bf2f(unsigned short s) {
    union { unsigned int u; float f; } v; v.u = ((unsigned int)s) << 16;
    return v.f;
}

// ---------------- K1a: P[v][n] = b[n] + sum_e emb[v][e] * Wx[n][e]; also zero flags ----------------
__global__ void k_embWx(const float* __restrict__ emb, const float* __restrict__ W,
                        const float* __restrict__ bb) {
    if (blockIdx.x == 0)
        for (int i = threadIdx.x; i < 16 * 64; i += 256) g_flag[i] = 0;   // fresh each launch
    __shared__ float e[E_];
    int v = blockIdx.x;
    e[threadIdx.x] = emb[(size_t)v * E_ + threadIdx.x];
    __syncthreads();
#pragma unroll
    for (int rep = 0; rep < 2; rep++) {
        int n = threadIdx.x + rep * 256;
        const float4* wr4 = (const float4*)(W + (size_t)n * (E_ + H_));
        float s = bb[n];
        for (int k = 0; k < E_ / 4; k++) {
            float4 wv = wr4[k];
            s += e[4*k] * wv.x + e[4*k+1] * wv.y + e[4*k+2] * wv.z + e[4*k+3] * wv.w;
        }
        g_P[v * H_ + n] = f2bf(s);
    }
}

// ---------------- K1b/K1c: weight -> MFMA B-fragment layout (bf16) ----------------
// Tile (nt,kt): lane l, elem j holds  Wmat[n = nt*16 + (l&15)][k = kt*32 + (l>>4)*8 + j]
__global__ void k_fragWh(const float* __restrict__ W) {
    int gid = blockIdx.x * blockDim.x + threadIdx.x;   // 512 tiles * 64 lanes
    int l = gid & 63, tile = gid >> 6;
    int kt = tile & 15, nt = tile >> 4;
    int n = nt * 16 + (l & 15), k0 = kt * 32 + (l >> 4) * 8;
    const float* src = W + (size_t)n * (E_ + H_) + E_ + k0;   // Wh = W[:,256:]
#pragma unroll
    for (int j = 0; j < 8; j++) g_Whf[(size_t)gid * 8 + j] = f2bf(src[j]);
}
__global__ void k_fragWd(const float* __restrict__ Wd) {
    int gid = blockIdx.x * blockDim.x + threadIdx.x;   // 256 tiles * 64 lanes
    int l = gid & 63, tile = gid >> 6;
    int kt = tile & 15, nt = tile >> 4;
    int n = nt * 16 + (l & 15), k0 = kt * 32 + (l >> 4) * 8;
    const float* src = Wd + (size_t)n * H_ + k0;
#pragma unroll
    for (int j = 0; j < 8; j++) g_Wdf[(size_t)gid * 8 + j] = f2bf(src[j]);
}

// ---------------- K2: recurrence, N-split x4, all-reg Wh, device-scope all-gather ----------------
// 64 blocks = 16 row-groups x 4 N-quarters; 512 thr = 8 waves; wave owns ONE ntile
// (16 n) x 16 kt = 64 pinned VGPRs (under the immovable 128-reg grant: R1-R6 showed
// 65536 regs/block no matter what, and demand-over-grant = catastrophic L2-scratch
// spill; 16-block designs must move >=100KB/step over the ~31-50 B/cy/CU L2 wall).
// Zero per-step weight traffic; instead a 4-block h all-gather through L3:
// relaxed agent-scope atomics (no wbl2 storms), parity-double-buffered g_ex (buffer
// reuse separated by a full flag round-trip), one padded flag counter per group.
// Per step: store quarter -> vmcnt(0) -> s_barrier -> tid0 atomicAdd -> all spin ->
// agent loads -> lds_h (XOR-swizzle byte^=(row&7)<<4) -> lgkmcnt(0) -> s_barrier.
__global__ void __launch_bounds__(512) k_rnn(const int* __restrict__ x,
                                             const float* __restrict__ h0,
                                             float* __restrict__ out) {
    __shared__ __align__(16) unsigned short lds_h[16 * 512];   // 16 KB, single buffer
    const int tid = threadIdx.x;
    const int w = tid >> 6, l = tid & 63;
    const int hi = l >> 4, lo = l & 15;
    const int g = blockIdx.x >> 2, q = blockIdx.x & 3;
    const int r0 = g * 16;
    const int ntile = q * 8 + w;                // global ntile 0..31
    const int n = ntile * 16 + lo;              // this thread's output column
    const int sw = (lo & 7) << 4;               // A-read swizzle

    // pinned Wh B-frags: 1 ntile x 16 kt = 16 frags = 64 VGPRs
    bf16x8 breg[16];
#pragma unroll
    for (int kt = 0; kt < 16; kt++)
        breg[kt] = *(const bf16x8*)(g_Whf + (ntile * 16 + kt) * 512 + l * 8);

    // stage h0 (fp32 -> bf16, swizzled): 512 thr x 16 floats
    {
        int row = tid >> 5;
        int c = (tid & 31) * 16;
        const float* hsrc = h0 + (size_t)(r0 + row) * H_ + c;
        us8 va, vb;
#pragma unroll
        for (int i = 0; i < 8; i++) ((unsigned short*)&va)[i] = f2bf(hsrc[i]);
#pragma unroll
        for (int i = 0; i < 8; i++) ((unsigned short*)&vb)[i] = f2bf(hsrc[8 + i]);
        char* hbw = (char*)lds_h + row * 1024;
        int cb = c * 2;
        *(us8*)(hbw + ((cb)      ^ ((row & 7) << 4))) = va;
        *(us8*)(hbw + ((cb + 16) ^ ((row & 7) << 4))) = vb;
    }

    // x(t=0) and u(t=0) = P[x0][n] for this thread's 4 rows (r = hi*4+rg)
    int xs0 = x[(r0 + hi * 4 + 0) * T_];
    int xs1 = x[(r0 + hi * 4 + 1) * T_];
    int xs2 = x[(r0 + hi * 4 + 2) * T_];
    int xs3 = x[(r0 + hi * 4 + 3) * T_];
    unsigned short u0 = g_P[xs0 * H_ + n];
    unsigned short u1 = g_P[xs1 * H_ + n];
    unsigned short u2 = g_P[xs2 * H_ + n];
    unsigned short u3 = g_P[xs3 * H_ + n];

    // per-thread hs element offsets (max ~134M < 2^31)
    const int eo0 = (r0 + hi * 4 + 0) * (T_ * H_) + n;
    const int eo1 = (r0 + hi * 4 + 1) * (T_ * H_) + n;
    const int eo2 = (r0 + hi * 4 + 2) * (T_ * H_) + n;
    const int eo3 = (r0 + hi * 4 + 3) * (T_ * H_) + n;

    unsigned short* hs = (unsigned short*)out;   // hs[b,t] bf16 in-place in d_out
    unsigned* const flag = &g_flag[g * 64];

    __syncthreads();

#pragma unroll 1
    for (int t = 0; t < T_; t++) {
        // prefetch x(t+1) (clamped)
        const int tn = (t < T_ - 1) ? t + 1 : t;
        const int xn0 = x[(r0 + hi * 4 + 0) * T_ + tn];
        const int xn1 = x[(r0 + hi * 4 + 1) * T_ + tn];
        const int xn2 = x[(r0 + hi * 4 + 2) * T_ + tn];
        const int xn3 = x[(r0 + hi * 4 + 3) * T_ + tn];

        // MFMA: acc = h @ Wh^T (+u via C-init), two chains to halve dep latency
        f32x4 aca = {bf2f(u0), bf2f(u1), bf2f(u2), bf2f(u3)};
        f32x4 acb = {0.f, 0.f, 0.f, 0.f};
        const char* hb = (const char*)lds_h;
#pragma unroll
        for (int kt = 0; kt < 16; kt += 2) {
            bf16x8 a0 = *(const bf16x8*)(hb + lo * 1024 + ((kt * 64 + hi * 16) ^ sw));
            bf16x8 a1 = *(const bf16x8*)(hb + lo * 1024 + (((kt + 1) * 64 + hi * 16) ^ sw));
            aca = __builtin_amdgcn_mfma_f32_16x16x32_bf16(a0, breg[kt],     aca, 0, 0, 0);
            acb = __builtin_amdgcn_mfma_f32_16x16x32_bf16(a1, breg[kt + 1], acb, 0, 0, 0);
        }

        // u(t+1) — issued here so L2 latency hides under epilogue+sync
        u0 = g_P[xn0 * H_ + n];
        u1 = g_P[xn1 * H_ + n];
        u2 = g_P[xn2 * H_ + n];
        u3 = g_P[xn3 * H_ + n];

        // epilogue: h_next = tanh(acc); hs stores + packed exchange words
        const int tb = t << 9;
        float v0 = aca[0] + acb[0], v1 = aca[1] + acb[1];
        float v2 = aca[2] + acb[2], v3 = aca[3] + acb[3];
        float t0 = 1.f - __fdividef(2.f, __expf(v0 + v0) + 1.f);
        float t1 = 1.f - __fdividef(2.f, __expf(v1 + v1) + 1.f);
        float t2 = 1.f - __fdividef(2.f, __expf(v2 + v2) + 1.f);
        float t3 = 1.f - __fdividef(2.f, __expf(v3 + v3) + 1.f);
        unsigned short h0v = f2bf(t0), h1v = f2bf(t1), h2v = f2bf(t2), h3v = f2bf(t3);
        hs[eo0 + tb] = h0v;
        hs[eo1 + tb] = h1v;
        hs[eo2 + tb] = h2v;
        hs[eo3 + tb] = h3v;
        const unsigned pr0 = (unsigned)h0v | ((unsigned)h1v << 16);
        const unsigned pr1 = (unsigned)h2v | ((unsigned)h3v << 16);
        unsigned* exb = &g_ex[(t + 1) & 1][(unsigned)(g * 512 + n) * 8 + hi * 2];
        __hip_atomic_store(exb,     pr0, __ATOMIC_RELAXED, __HIP_MEMORY_SCOPE_AGENT);
        __hip_atomic_store(exb + 1, pr1, __ATOMIC_RELAXED, __HIP_MEMORY_SCOPE_AGENT);

        // drain all VMEM (hs + exchange in L3), then block-wide rendezvous
        __builtin_amdgcn_sched_barrier(0);
        asm volatile("s_waitcnt vmcnt(0)" ::: "memory");
        __builtin_amdgcn_s_barrier();
        if (tid == 0)
            __hip_atomic_fetch_add(flag, 1u, __ATOMIC_RELAXED, __HIP_MEMORY_SCOPE_AGENT);

        // spin until all 4 quarter-blocks of this group posted step t
        const unsigned tgt = 4u * (unsigned)(t + 1);
        while (__hip_atomic_load(flag, __ATOMIC_RELAXED, __HIP_MEMORY_SCOPE_AGENT) < tgt)
            __builtin_amdgcn_s_sleep(1);
        __builtin_amdgcn_sched_barrier(0);

        // all-gather: thread tid owns column n'=tid; 4 x u64 agent loads = rows 0..15
        const unsigned* exr = &g_ex[(t + 1) & 1][(unsigned)(g * 512 + tid) * 8];
        char* hw = (char*)lds_h;
#pragma unroll
        for (int j = 0; j < 4; j++) {
            unsigned long long d = __hip_atomic_load(
                (const unsigned long long*)(exr + 2 * j),
                __ATOMIC_RELAXED, __HIP_MEMORY_SCOPE_AGENT);
            const int r = 4 * j;
            *(unsigned short*)(hw + (r + 0) * 1024 + ((2 * tid) ^ (((r + 0) & 7) << 4))) = (unsigned short)(d);
            *(unsigned short*)(hw + (r + 1) * 1024 + ((2 * tid) ^ (((r + 1) & 7) << 4))) = (unsigned short)(d >> 16);
            *(unsigned short*)(hw + (r + 2) * 1024 + ((2 * tid) ^ (((r + 2) & 7) << 4))) = (unsigned short)(d >> 32);
            *(unsigned short*)(hw + (r + 3) * 1024 + ((2 * tid) ^ (((r + 3) & 7) << 4))) = (unsigned short)(d >> 48);
        }
        asm volatile("s_waitcnt lgkmcnt(0)" ::: "memory");
        __builtin_amdgcn_s_barrier();
    }

    // h_final (fp32): this thread's 4 (row, n) cells from the final lds_h
    float* hfin = out + (size_t)B_ * T_ * O_;
#pragma unroll
    for (int rg = 0; rg < 4; rg++) {
        const int r = hi * 4 + rg;
        unsigned short hv = *(const unsigned short*)((const char*)lds_h + r * 1024 +
                                                     ((2 * n) ^ ((r & 7) << 4)));
        hfin[(r0 + r) * H_ + n] = bf2f(hv);
    }
}

// ---------------- K3: outputs = hs @ Wd^T + bd, in-place over hs slots ----------------
// 1024 blocks x 256 (b,t)-rows; wave w: 32 rows x all 256 outs. Reads bf16 hs from the
// exact d_out bytes it later overwrites with fp32 outputs (reads precede writes per wave).
__launch_bounds__(512, 2)
__global__ void k_out(const float* __restrict__ bd, float* out) {
    int tid = threadIdx.x;
    int w = tid >> 6, l = tid & 63;
    int hi = l >> 4, lo = l & 15;
    size_t m0 = (size_t)blockIdx.x * 256 + w * 32;
    const unsigned short* hsb = (const unsigned short*)out;
    float bdv[16];
#pragma unroll
    for (int nt = 0; nt < 16; nt++) bdv[nt] = bd[nt * 16 + lo];
    f32x4 acc[2][16];
#pragma unroll
    for (int m = 0; m < 2; m++)
#pragma unroll
        for (int nt = 0; nt < 16; nt++) { acc[m][nt][0] = 0.f; acc[m][nt][1] = 0.f; acc[m][nt][2] = 0.f; acc[m][nt][3] = 0.f; }
#pragma unroll 2
    for (int kt = 0; kt < 16; kt++) {
        bf16x8 a0 = *(const bf16x8*)(hsb + (m0 + lo) * 512 + kt * 32 + hi * 8);
        bf16x8 a1 = *(const bf16x8*)(hsb + (m0 + 16 + lo) * 512 + kt * 32 + hi * 8);
#pragma unroll
        for (int nt = 0; nt < 16; nt++) {
            bf16x8 bf = *(const bf16x8*)(g_Wdf + (size_t)(nt * 16 + kt) * 512 + l * 8);
            acc[0][nt] = __builtin_amdgcn_mfma_f32_16x16x32_bf16(a0, bf, acc[0][nt], 0, 0, 0);
            acc[1][nt] = __builtin_amdgcn_mfma_f32_16x16x32_bf16(a1, bf, acc[1][nt], 0, 0, 0);
        }
    }
#pragma unroll
    for (int m = 0; m < 2; m++)
#pragma unroll
        for (int nt = 0; nt < 16; nt++)
#pragma unroll
            for (int rg = 0; rg < 4; rg++) {
                size_t row = m0 + m * 16 + hi * 4 + rg;
                out[row * O_ + nt * 16 + lo] = acc[m][nt][rg] + bdv[nt];
            }
}

extern "C" void kernel_launch(void* const* d_in, const int* in_sizes, int n_in,
                              void* d_out, int out_size, void* d_ws, size_t ws_size,
                              hipStream_t stream) {
    const int*   x   = (const int*)d_in[0];
    const float* h0  = (const float*)d_in[1];
    const float* emb = (const float*)d_in[2];
    const float* W   = (const float*)d_in[3];
    const float* b   = (const float*)d_in[4];
    const float* Wd  = (const float*)d_in[5];
    const float* bd  = (const float*)d_in[6];
    float* out = (float*)d_out;

    k_embWx<<<dim3(V_), dim3(256), 0, stream>>>(emb, W, b);
    k_fragWh<<<dim3(128), dim3(256), 0, stream>>>(W);
    k_fragWd<<<dim3(64), dim3(256), 0, stream>>>(Wd);
    k_rnn<<<dim3(64), dim3(512), 0, stream>>>(x, h0, out);
    k_out<<<dim3(1024), dim3(512), 0, stream>>>(bd, out);
}